// Round 1
// baseline (4431.340 us; speedup 1.0000x reference)
//
#include <hip/hip_runtime.h>

#define NFEAT 128
#define NHID 64

// ---------- edge-index dtype detection ----------
// JAX reference says int64 but default JAX config downcasts to int32.
// For little-endian int64 with values < 2^31, every odd int32 word is 0.
// OR-reduce the first 4096 int32 words' odd positions: all zero => int64.
__global__ void k_detect(const int* __restrict__ ei_words, int nwords, int* flag) {
    __shared__ int s_or;
    if (threadIdx.x == 0) s_or = 0;
    __syncthreads();
    int acc = 0;
    for (int i = 1 + 2 * (int)threadIdx.x; i < nwords; i += 2 * (int)blockDim.x)
        acc |= ei_words[i];
    atomicOr(&s_or, acc);
    __syncthreads();
    if (threadIdx.x == 0) *flag = (s_or == 0) ? 1 : 0;
}

__device__ __forceinline__ int edge_idx(const int* __restrict__ ei, int is64,
                                        long long E, long long e, int which) {
    long long pos = which ? (E + e) : e;
    return is64 ? ei[2 * pos] : ei[pos];
}

// ---------- degree (in-degree on dst; self-loop added in k_dinv) ----------
__global__ void k_deg(const int* __restrict__ ei, const int* __restrict__ flag,
                      long long E, float* deg) {
    long long e = (long long)blockIdx.x * blockDim.x + threadIdx.x;
    if (e >= E) return;
    int is64 = *flag;
    int d = edge_idx(ei, is64, E, e, 1);
    atomicAdd(&deg[d], 1.0f);
}

__global__ void k_dinv(float* deg, int N) {
    int i = blockIdx.x * blockDim.x + threadIdx.x;
    if (i >= N) return;
    deg[i] = rsqrtf(deg[i] + 1.0f);   // +1 = self loop
}

// ---------- GEMM1: x[N,128] @ W1[128,64] -> xw1[N,64] ----------
__global__ __launch_bounds__(256) void k_gemm1(const float* __restrict__ x,
                                               const float* __restrict__ W1,
                                               float* __restrict__ xw1, int N) {
    __shared__ float sW[NFEAT * NHID];   // 32 KB: whole W1
    __shared__ float sx[4 * NFEAT];
    for (int i = threadIdx.x; i < NFEAT * NHID; i += 256) sW[i] = W1[i];
    int row0 = blockIdx.x * 4;
    for (int i = threadIdx.x; i < 4 * NFEAT; i += 256) {
        int rr = i >> 7, kk = i & 127;
        int row = row0 + rr;
        sx[i] = (row < N) ? x[(long long)row * NFEAT + kk] : 0.0f;
    }
    __syncthreads();
    int r = threadIdx.x >> 6;
    int c = threadIdx.x & 63;
    float acc = 0.f;
#pragma unroll
    for (int k = 0; k < NFEAT; ++k) acc += sx[r * NFEAT + k] * sW[k * NHID + c];
    int row = row0 + r;
    if (row < N) xw1[(long long)row * NHID + c] = acc;
}

// ---------- GEMM2: h[N,64] @ W2[64,128] -> hw2[N,128] ----------
__global__ __launch_bounds__(256) void k_gemm2(const float* __restrict__ h,
                                               const float* __restrict__ W2,
                                               float* __restrict__ hw2, int N) {
    __shared__ float sW[NHID * NFEAT];   // 32 KB: whole W2
    __shared__ float sh[2 * NHID];
    for (int i = threadIdx.x; i < NHID * NFEAT; i += 256) sW[i] = W2[i];
    int row0 = blockIdx.x * 2;
    for (int i = threadIdx.x; i < 2 * NHID; i += 256) {
        int rr = i >> 6, kk = i & 63;
        int row = row0 + rr;
        sh[i] = (row < N) ? h[(long long)row * NHID + kk] : 0.0f;
    }
    __syncthreads();
    int r = threadIdx.x >> 7;
    int c = threadIdx.x & 127;
    float acc = 0.f;
#pragma unroll
    for (int k = 0; k < NHID; ++k) acc += sh[r * NHID + k] * sW[k * NFEAT + c];
    int row = row0 + r;
    if (row < N) hw2[(long long)row * NFEAT + c] = acc;
}

// ---------- edge scatter: acc[dst] += dinv[src]*dinv[dst] * feat[src] ----------
template <int F>
__global__ void k_scatter(const int* __restrict__ ei, const int* __restrict__ flag,
                          long long E, const float* __restrict__ dinv,
                          const float* __restrict__ feat, float* acc) {
    const int CH = F / 4;   // float4 chunks per edge
    long long t = (long long)blockIdx.x * blockDim.x + threadIdx.x;
    long long e = t / CH;
    int c = (int)(t % CH) * 4;
    if (e >= E) return;
    int is64 = *flag;
    int s = edge_idx(ei, is64, E, e, 0);
    int d = edge_idx(ei, is64, E, e, 1);
    float norm = dinv[s] * dinv[d];
    const float4 v = *(const float4*)&feat[(long long)s * F + c];
    float* base = &acc[(long long)d * F + c];
    atomicAdd(base + 0, norm * v.x);
    atomicAdd(base + 1, norm * v.y);
    atomicAdd(base + 2, norm * v.z);
    atomicAdd(base + 3, norm * v.w);
}

// ---------- epilogues ----------
__global__ void k_finish1(const float* __restrict__ xw1, const float* __restrict__ dinv,
                          const float* __restrict__ b1, float* acc1, long long total) {
    long long t = (long long)blockIdx.x * blockDim.x + threadIdx.x;
    if (t >= total) return;
    int i = (int)(t / NHID);
    int c = (int)(t % NHID);
    float di = dinv[i];
    float v = acc1[t] + di * di * xw1[t] + b1[c];
    acc1[t] = v > 0.f ? v : 0.f;   // ReLU, in-place -> h
}

__global__ void k_finish2(const float* __restrict__ hw2, const float* __restrict__ dinv,
                          const float* __restrict__ b2, float* out, long long total) {
    long long t = (long long)blockIdx.x * blockDim.x + threadIdx.x;
    if (t >= total) return;
    int i = (int)(t / NFEAT);
    int c = (int)(t % NFEAT);
    float di = dinv[i];
    out[t] += di * di * hw2[t] + b2[c];
}

extern "C" void kernel_launch(void* const* d_in, const int* in_sizes, int n_in,
                              void* d_out, int out_size, void* d_ws, size_t ws_size,
                              hipStream_t stream) {
    const float* x  = (const float*)d_in[0];
    const int*   ei = (const int*)d_in[1];
    const float* W1 = (const float*)d_in[2];
    const float* b1 = (const float*)d_in[3];
    const float* W2 = (const float*)d_in[4];
    const float* b2 = (const float*)d_in[5];
    float* out = (float*)d_out;

    const int N = in_sizes[0] / NFEAT;          // 100000
    const long long E = in_sizes[1] / 2;        // 1600000

    // workspace layout
    char* w = (char*)d_ws;
    int*   flag = (int*)w;                       // 4 B (+pad to 256)
    float* dinv = (float*)(w + 256);             // N
    float* xw1  = dinv + N;                      // N*64
    float* acc1 = xw1 + (size_t)N * NHID;        // N*64 (becomes h after finish1)
    float* hw2  = acc1 + (size_t)N * NHID;       // N*128

    // zero accumulators (ws/out are poisoned 0xAA before every launch)
    hipMemsetAsync(dinv, 0, (size_t)N * sizeof(float), stream);
    hipMemsetAsync(acc1, 0, (size_t)N * NHID * sizeof(float), stream);
    hipMemsetAsync(out, 0, (size_t)N * NFEAT * sizeof(float), stream);

    k_detect<<<1, 256, 0, stream>>>(ei, 4096, flag);
    k_deg<<<(int)((E + 255) / 256), 256, 0, stream>>>(ei, flag, E, dinv);
    k_dinv<<<(N + 255) / 256, 256, 0, stream>>>(dinv, N);

    k_gemm1<<<(N + 3) / 4, 256, 0, stream>>>(x, W1, xw1, N);

    long long t1 = E * (NHID / 4);
    k_scatter<NHID><<<(int)((t1 + 255) / 256), 256, 0, stream>>>(ei, flag, E, dinv, xw1, acc1);
    long long n1 = (long long)N * NHID;
    k_finish1<<<(int)((n1 + 255) / 256), 256, 0, stream>>>(xw1, dinv, b1, acc1, n1);

    k_gemm2<<<(N + 1) / 2, 256, 0, stream>>>(acc1, W2, hw2, N);

    long long t2 = E * (NFEAT / 4);
    k_scatter<NFEAT><<<(int)((t2 + 255) / 256), 256, 0, stream>>>(ei, flag, E, dinv, hw2, out);
    long long n2 = (long long)N * NFEAT;
    k_finish2<<<(int)((n2 + 255) / 256), 256, 0, stream>>>(hw2, dinv, b2, out, n2);
}

// Round 2
// 703.382 us; speedup vs baseline: 6.3000x; 6.3000x over previous
//
#include <hip/hip_runtime.h>

#define NFEAT 128
#define NHID 64

// ---------- edge-index dtype detection ----------
// JAX reference says int64 but default JAX config downcasts to int32.
// For little-endian int64 with values < 2^31, every odd int32 word is 0.
__global__ void k_detect(const int* __restrict__ ei_words, int nwords, int* flag) {
    __shared__ int s_or;
    if (threadIdx.x == 0) s_or = 0;
    __syncthreads();
    int acc = 0;
    for (int i = 1 + 2 * (int)threadIdx.x; i < nwords; i += 2 * (int)blockDim.x)
        acc |= ei_words[i];
    atomicOr(&s_or, acc);
    __syncthreads();
    if (threadIdx.x == 0) *flag = (s_or == 0) ? 1 : 0;
}

__device__ __forceinline__ int edge_idx(const int* __restrict__ ei, int is64,
                                        long long E, long long e, int which) {
    long long pos = which ? (E + e) : e;
    return is64 ? ei[2 * pos] : ei[pos];
}

// ---------- per-dst edge count (int) ----------
__global__ void k_count(const int* __restrict__ ei, const int* __restrict__ flag,
                        long long E, int* cnt) {
    long long e = (long long)blockIdx.x * blockDim.x + threadIdx.x;
    if (e >= E) return;
    int is64 = *flag;
    int d = edge_idx(ei, is64, E, e, 1);
    atomicAdd(&cnt[d], 1);
}

__global__ void k_dinv(const int* __restrict__ cnt, float* dinv, int N) {
    int i = blockIdx.x * blockDim.x + threadIdx.x;
    if (i >= N) return;
    dinv[i] = rsqrtf((float)cnt[i] + 1.0f);   // +1 = self loop
}

// ---------- exclusive scan (3 kernels, chunk=1024) ----------
__global__ __launch_bounds__(256) void k_scan1(const int* __restrict__ cnt, int N,
                                               int* off, int* chunksum) {
    __shared__ int s[256];
    int t = threadIdx.x;
    int base = blockIdx.x * 1024 + t * 4;
    int v0 = (base + 0 < N) ? cnt[base + 0] : 0;
    int v1 = (base + 1 < N) ? cnt[base + 1] : 0;
    int v2 = (base + 2 < N) ? cnt[base + 2] : 0;
    int v3 = (base + 3 < N) ? cnt[base + 3] : 0;
    int sum = v0 + v1 + v2 + v3;
    s[t] = sum;
    __syncthreads();
    for (int d = 1; d < 256; d <<= 1) {
        int val = (t >= d) ? s[t - d] : 0;
        __syncthreads();
        s[t] += val;
        __syncthreads();
    }
    int run = s[t] - sum;   // exclusive prefix within chunk
    if (base + 0 <= N) off[base + 0] = run; run += v0;
    if (base + 1 <= N) off[base + 1] = run; run += v1;
    if (base + 2 <= N) off[base + 2] = run; run += v2;
    if (base + 3 <= N) off[base + 3] = run;
    if (t == 255) chunksum[blockIdx.x] = s[255];
}

__global__ __launch_bounds__(256) void k_scan2(const int* __restrict__ chunksum,
                                               int* chunkoff, int nchunks) {
    __shared__ int s[256];
    int t = threadIdx.x;
    int v = (t < nchunks) ? chunksum[t] : 0;
    s[t] = v;
    __syncthreads();
    for (int d = 1; d < 256; d <<= 1) {
        int val = (t >= d) ? s[t - d] : 0;
        __syncthreads();
        s[t] += val;
        __syncthreads();
    }
    chunkoff[t] = s[t] - v;   // exclusive
}

__global__ void k_scan3(int* off, const int* __restrict__ chunkoff, int N, int* cursor) {
    int i = blockIdx.x * 256 + threadIdx.x;
    if (i > N) return;
    int v = off[i] + chunkoff[i >> 10];
    off[i] = v;
    if (i < N) cursor[i] = v;
}

// ---------- CSR fill: bucket src ids by dst ----------
__global__ void k_fill(const int* __restrict__ ei, const int* __restrict__ flag,
                       long long E, int* cursor, int* esrc) {
    long long e = (long long)blockIdx.x * blockDim.x + threadIdx.x;
    if (e >= E) return;
    int is64 = *flag;
    int s = edge_idx(ei, is64, E, e, 0);
    int d = edge_idx(ei, is64, E, e, 1);
    int pos = atomicAdd(&cursor[d], 1);
    esrc[pos] = s;
}

// ---------- GEMM1: x[N,128] @ W1[128,64] -> xw1[N,64] ----------
__global__ __launch_bounds__(256) void k_gemm1(const float* __restrict__ x,
                                               const float* __restrict__ W1,
                                               float* __restrict__ xw1, int N) {
    __shared__ float sW[NFEAT * NHID];   // 32 KB: whole W1
    __shared__ float sx[4 * NFEAT];
    for (int i = threadIdx.x; i < NFEAT * NHID; i += 256) sW[i] = W1[i];
    int row0 = blockIdx.x * 4;
    for (int i = threadIdx.x; i < 4 * NFEAT; i += 256) {
        int rr = i >> 7, kk = i & 127;
        int row = row0 + rr;
        sx[i] = (row < N) ? x[(long long)row * NFEAT + kk] : 0.0f;
    }
    __syncthreads();
    int r = threadIdx.x >> 6;
    int c = threadIdx.x & 63;
    float acc = 0.f;
#pragma unroll
    for (int k = 0; k < NFEAT; ++k) acc += sx[r * NFEAT + k] * sW[k * NHID + c];
    int row = row0 + r;
    if (row < N) xw1[(long long)row * NHID + c] = acc;
}

// ---------- aggregation: one wave per dst node, 64 lanes = 64 feats ----------
// out[d] = dinv[d] * sum_e dinv[src]*feat[src] + dinv[d]^2*self[d] (+bias, relu)
template <int RELU, int BIAS>
__global__ __launch_bounds__(256) void k_agg(const int* __restrict__ off,
                                             const int* __restrict__ esrc,
                                             const float* __restrict__ dinv,
                                             const float* __restrict__ feat,
                                             const float* __restrict__ bias,
                                             float* __restrict__ outp, int N) {
    int wave = threadIdx.x >> 6;
    int lane = threadIdx.x & 63;
    int d = blockIdx.x * 4 + wave;
    if (d >= N) return;
    int lo = off[d], hi = off[d + 1];
    float dd = dinv[d];
    float acc = 0.f;
    int e = lo;
    for (; e + 4 <= hi; e += 4) {
        int s0 = esrc[e + 0], s1 = esrc[e + 1], s2 = esrc[e + 2], s3 = esrc[e + 3];
        float v0 = feat[(long long)s0 * NHID + lane];
        float v1 = feat[(long long)s1 * NHID + lane];
        float v2 = feat[(long long)s2 * NHID + lane];
        float v3 = feat[(long long)s3 * NHID + lane];
        float n0 = dinv[s0], n1 = dinv[s1], n2 = dinv[s2], n3 = dinv[s3];
        acc += n0 * v0 + n1 * v1 + n2 * v2 + n3 * v3;
    }
    for (; e < hi; ++e) {
        int s = esrc[e];
        acc += dinv[s] * feat[(long long)s * NHID + lane];
    }
    acc *= dd;                                        // fold dst-side norm
    acc += dd * dd * feat[(long long)d * NHID + lane];  // self loop
    if (BIAS) acc += bias[lane];
    if (RELU) acc = fmaxf(acc, 0.f);
    outp[(long long)d * NHID + lane] = acc;
}

// ---------- GEMM2: agg2[N,64] @ W2[64,128] + b2 -> out[N,128] ----------
__global__ __launch_bounds__(256) void k_gemm2(const float* __restrict__ h,
                                               const float* __restrict__ W2,
                                               const float* __restrict__ b2,
                                               float* __restrict__ out, int N) {
    __shared__ float sW[NHID * NFEAT];   // 32 KB: whole W2
    __shared__ float sh[2 * NHID];
    for (int i = threadIdx.x; i < NHID * NFEAT; i += 256) sW[i] = W2[i];
    int row0 = blockIdx.x * 2;
    for (int i = threadIdx.x; i < 2 * NHID; i += 256) {
        int rr = i >> 6, kk = i & 63;
        int row = row0 + rr;
        sh[i] = (row < N) ? h[(long long)row * NHID + kk] : 0.0f;
    }
    __syncthreads();
    int r = threadIdx.x >> 7;
    int c = threadIdx.x & 127;
    float acc = 0.f;
#pragma unroll
    for (int k = 0; k < NHID; ++k) acc += sh[r * NHID + k] * sW[k * NFEAT + c];
    int row = row0 + r;
    if (row < N) out[(long long)row * NFEAT + c] = acc + b2[c];
}

extern "C" void kernel_launch(void* const* d_in, const int* in_sizes, int n_in,
                              void* d_out, int out_size, void* d_ws, size_t ws_size,
                              hipStream_t stream) {
    const float* x  = (const float*)d_in[0];
    const int*   ei = (const int*)d_in[1];
    const float* W1 = (const float*)d_in[2];
    const float* b1 = (const float*)d_in[3];
    const float* W2 = (const float*)d_in[4];
    const float* b2 = (const float*)d_in[5];
    float* out = (float*)d_out;

    const int N = in_sizes[0] / NFEAT;          // 100000
    const long long E = in_sizes[1] / 2;        // 1600000
    const int nchunks = (N + 1 + 1023) / 1024;  // scan chunks (<=256 required)

    // workspace layout
    char* w = (char*)d_ws;
    int*   flag     = (int*)w;                          // 4 B (pad 256)
    int*   cnt      = (int*)(w + 256);                  // N
    int*   off      = cnt + N;                          // N+1
    int*   cursor   = off + N + 1;                      // N
    int*   chunksum = cursor + N;                       // 256
    int*   chunkoff = chunksum + 256;                   // 256
    float* dinv     = (float*)(chunkoff + 256);         // N
    int*   esrc     = (int*)(dinv + N);                 // E
    float* xw1      = (float*)(esrc + E);               // N*64
    float* h        = xw1 + (size_t)N * NHID;           // N*64
    float* agg2     = h + (size_t)N * NHID;             // N*64

    hipMemsetAsync(cnt, 0, (size_t)N * sizeof(int), stream);

    k_detect<<<1, 256, 0, stream>>>(ei, 4096, flag);
    k_count<<<(int)((E + 255) / 256), 256, 0, stream>>>(ei, flag, E, cnt);
    k_dinv<<<(N + 255) / 256, 256, 0, stream>>>(cnt, dinv, N);

    k_scan1<<<nchunks, 256, 0, stream>>>(cnt, N, off, chunksum);
    k_scan2<<<1, 256, 0, stream>>>(chunksum, chunkoff, nchunks);
    k_scan3<<<(N + 1 + 255) / 256, 256, 0, stream>>>(off, chunkoff, N, cursor);
    k_fill<<<(int)((E + 255) / 256), 256, 0, stream>>>(ei, flag, E, cursor, esrc);

    k_gemm1<<<(N + 3) / 4, 256, 0, stream>>>(x, W1, xw1, N);

    // layer 1 aggregate + self-loop + bias + relu -> h
    k_agg<1, 1><<<(N + 3) / 4, 256, 0, stream>>>(off, esrc, dinv, xw1, b1, h, N);
    // layer 2 aggregate (no bias/relu) -> agg2
    k_agg<0, 0><<<(N + 3) / 4, 256, 0, stream>>>(off, esrc, dinv, h, nullptr, agg2, N);

    k_gemm2<<<(N + 1) / 2, 256, 0, stream>>>(agg2, W2, b2, out, N);
}

// Round 3
// 536.597 us; speedup vs baseline: 8.2582x; 1.3108x over previous
//
#include <hip/hip_runtime.h>

#define NFEAT 128
#define NHID 64

// ---------- edge-index dtype detection ----------
// JAX reference says int64 but default JAX config downcasts to int32.
// For little-endian int64 with values < 2^31, every odd int32 word is 0.
__global__ void k_detect(const int* __restrict__ ei_words, int nwords, int* flag) {
    __shared__ int s_or;
    if (threadIdx.x == 0) s_or = 0;
    __syncthreads();
    int acc = 0;
    for (int i = 1 + 2 * (int)threadIdx.x; i < nwords; i += 2 * (int)blockDim.x)
        acc |= ei_words[i];
    atomicOr(&s_or, acc);
    __syncthreads();
    if (threadIdx.x == 0) *flag = (s_or == 0) ? 1 : 0;
}

__device__ __forceinline__ int edge_idx(const int* __restrict__ ei, int is64,
                                        long long E, long long e, int which) {
    long long pos = which ? (E + e) : e;
    return is64 ? ei[2 * pos] : ei[pos];
}

// ---------- per-dst edge count ----------
__global__ void k_count(const int* __restrict__ ei, const int* __restrict__ flag,
                        long long E, int* cnt) {
    long long e = (long long)blockIdx.x * blockDim.x + threadIdx.x;
    if (e >= E) return;
    int is64 = *flag;
    int d = edge_idx(ei, is64, E, e, 1);
    atomicAdd(&cnt[d], 1);
}

__global__ void k_dinv(const int* __restrict__ cnt, float* dinv, int N) {
    int i = blockIdx.x * blockDim.x + threadIdx.x;
    if (i >= N) return;
    dinv[i] = rsqrtf((float)cnt[i] + 1.0f);   // +1 = self loop
}

// ---------- exclusive scan (3 kernels, chunk=1024) ----------
__global__ __launch_bounds__(256) void k_scan1(const int* __restrict__ cnt, int N,
                                               int* off, int* chunksum) {
    __shared__ int s[256];
    int t = threadIdx.x;
    int base = blockIdx.x * 1024 + t * 4;
    int v0 = (base + 0 < N) ? cnt[base + 0] : 0;
    int v1 = (base + 1 < N) ? cnt[base + 1] : 0;
    int v2 = (base + 2 < N) ? cnt[base + 2] : 0;
    int v3 = (base + 3 < N) ? cnt[base + 3] : 0;
    int sum = v0 + v1 + v2 + v3;
    s[t] = sum;
    __syncthreads();
    for (int d = 1; d < 256; d <<= 1) {
        int val = (t >= d) ? s[t - d] : 0;
        __syncthreads();
        s[t] += val;
        __syncthreads();
    }
    int run = s[t] - sum;   // exclusive prefix within chunk
    if (base + 0 <= N) off[base + 0] = run; run += v0;
    if (base + 1 <= N) off[base + 1] = run; run += v1;
    if (base + 2 <= N) off[base + 2] = run; run += v2;
    if (base + 3 <= N) off[base + 3] = run;
    if (t == 255) chunksum[blockIdx.x] = s[255];
}

__global__ __launch_bounds__(256) void k_scan2(const int* __restrict__ chunksum,
                                               int* chunkoff, int nchunks) {
    __shared__ int s[256];
    int t = threadIdx.x;
    int v = (t < nchunks) ? chunksum[t] : 0;
    s[t] = v;
    __syncthreads();
    for (int d = 1; d < 256; d <<= 1) {
        int val = (t >= d) ? s[t - d] : 0;
        __syncthreads();
        s[t] += val;
        __syncthreads();
    }
    chunkoff[t] = s[t] - v;   // exclusive
}

__global__ void k_scan3(int* off, const int* __restrict__ chunkoff, int N, int* cursor) {
    int i = blockIdx.x * 256 + threadIdx.x;
    if (i > N) return;
    int v = off[i] + chunkoff[i >> 10];
    off[i] = v;
    if (i < N) cursor[i] = v;
}

// ---------- CSR fill: bucket src ids by dst ----------
__global__ void k_fill(const int* __restrict__ ei, const int* __restrict__ flag,
                       long long E, int* cursor, int* esrc) {
    long long e = (long long)blockIdx.x * blockDim.x + threadIdx.x;
    if (e >= E) return;
    int is64 = *flag;
    int s = edge_idx(ei, is64, E, e, 0);
    int d = edge_idx(ei, is64, E, e, 1);
    int pos = atomicAdd(&cursor[d], 1);
    esrc[pos] = s;
}

// ---------- register-blocked fp32 GEMM helpers ----------
__device__ __forceinline__ void fma4(float (&acc)[4], float a, const float4& b) {
    acc[0] += a * b.x; acc[1] += a * b.y; acc[2] += a * b.z; acc[3] += a * b.w;
}

// ---------- GEMM1: x[N,128] @ W1[128,64] -> xw1[N,64] ----------
// tile 64 rows x 64 cols, thread = 4x4, full K staged (32KB A + 32KB B)
__global__ __launch_bounds__(256) void k_gemm1(const float* __restrict__ x,
                                               const float* __restrict__ W1,
                                               float* __restrict__ xw1, int N) {
    __shared__ float sA[64 * NFEAT];   // 32 KB
    __shared__ float sB[NFEAT * NHID]; // 32 KB
    for (int i = threadIdx.x; i < NFEAT * NHID / 4; i += 256)
        ((float4*)sB)[i] = ((const float4*)W1)[i];
    int row0 = blockIdx.x * 64;
    for (int i = threadIdx.x; i < 64 * NFEAT / 4; i += 256) {
        int r = i >> 5, c4 = i & 31;
        int row = row0 + r;
        ((float4*)sA)[i] = (row < N) ? ((const float4*)x)[(long long)row * 32 + c4]
                                     : make_float4(0.f, 0.f, 0.f, 0.f);
    }
    __syncthreads();
    int rg = threadIdx.x >> 4;   // 0..15 -> 4 rows each
    int cg = threadIdx.x & 15;   // 0..15 -> 4 cols each
    int r0 = rg * 4, c0 = cg * 4;
    float acc[4][4] = {};
#pragma unroll 4
    for (int k = 0; k < NFEAT; k += 4) {
        float4 a0 = *(const float4*)&sA[(r0 + 0) * NFEAT + k];
        float4 a1 = *(const float4*)&sA[(r0 + 1) * NFEAT + k];
        float4 a2 = *(const float4*)&sA[(r0 + 2) * NFEAT + k];
        float4 a3 = *(const float4*)&sA[(r0 + 3) * NFEAT + k];
        float4 b0 = *(const float4*)&sB[(k + 0) * NHID + c0];
        float4 b1 = *(const float4*)&sB[(k + 1) * NHID + c0];
        float4 b2v = *(const float4*)&sB[(k + 2) * NHID + c0];
        float4 b3 = *(const float4*)&sB[(k + 3) * NHID + c0];
        fma4(acc[0], a0.x, b0); fma4(acc[0], a0.y, b1); fma4(acc[0], a0.z, b2v); fma4(acc[0], a0.w, b3);
        fma4(acc[1], a1.x, b0); fma4(acc[1], a1.y, b1); fma4(acc[1], a1.z, b2v); fma4(acc[1], a1.w, b3);
        fma4(acc[2], a2.x, b0); fma4(acc[2], a2.y, b1); fma4(acc[2], a2.z, b2v); fma4(acc[2], a2.w, b3);
        fma4(acc[3], a3.x, b0); fma4(acc[3], a3.y, b1); fma4(acc[3], a3.z, b2v); fma4(acc[3], a3.w, b3);
    }
#pragma unroll
    for (int r = 0; r < 4; ++r) {
        int row = row0 + r0 + r;
        if (row < N) {
            float4 o = make_float4(acc[r][0], acc[r][1], acc[r][2], acc[r][3]);
            *(float4*)&xw1[(long long)row * NHID + c0] = o;
        }
    }
}

// ---------- GEMM2: agg2[N,64] @ W2[64,128] + b2 -> out[N,128] ----------
// tile 64 rows x 128 cols, thread = 8x4, grid-stride over tiles
__global__ __launch_bounds__(256) void k_gemm2(const float* __restrict__ h,
                                               const float* __restrict__ W2,
                                               const float* __restrict__ b2,
                                               float* __restrict__ out, int N, int ntiles) {
    __shared__ float sB[NHID * NFEAT]; // 32 KB
    __shared__ float sA[64 * NHID];    // 16 KB
    for (int i = threadIdx.x; i < NHID * NFEAT / 4; i += 256)
        ((float4*)sB)[i] = ((const float4*)W2)[i];
    int rg = threadIdx.x >> 5;   // 0..7 -> 8 rows each
    int cg = threadIdx.x & 31;   // 0..31 -> 4 cols each
    int c0 = cg * 4;
    float4 bias = *(const float4*)&b2[c0];
    for (int tile = blockIdx.x; tile < ntiles; tile += gridDim.x) {
        int row0 = tile * 64;
        __syncthreads();   // protect sA before restage
        for (int i = threadIdx.x; i < 64 * NHID / 4; i += 256) {
            int r = i >> 4, c4 = i & 15;
            int row = row0 + r;
            ((float4*)sA)[i] = (row < N) ? ((const float4*)h)[(long long)row * 16 + c4]
                                         : make_float4(0.f, 0.f, 0.f, 0.f);
        }
        __syncthreads();
        float acc[8][4] = {};
#pragma unroll 2
        for (int k = 0; k < NHID; k += 4) {
            float4 b0 = *(const float4*)&sB[(k + 0) * NFEAT + c0];
            float4 b1 = *(const float4*)&sB[(k + 1) * NFEAT + c0];
            float4 b2f = *(const float4*)&sB[(k + 2) * NFEAT + c0];
            float4 b3 = *(const float4*)&sB[(k + 3) * NFEAT + c0];
#pragma unroll
            for (int r = 0; r < 8; ++r) {
                float4 a = *(const float4*)&sA[(rg * 8 + r) * NHID + k];
                fma4(acc[r], a.x, b0); fma4(acc[r], a.y, b1);
                fma4(acc[r], a.z, b2f); fma4(acc[r], a.w, b3);
            }
        }
#pragma unroll
        for (int r = 0; r < 8; ++r) {
            int row = row0 + rg * 8 + r;
            if (row < N) {
                float4 o = make_float4(acc[r][0] + bias.x, acc[r][1] + bias.y,
                                       acc[r][2] + bias.z, acc[r][3] + bias.w);
                *(float4*)&out[(long long)row * NFEAT + c0] = o;
            }
        }
    }
}

// ---------- aggregation: one wave per dst node, 64 lanes = 64 feats ----------
template <int RELU, int BIAS>
__global__ __launch_bounds__(256) void k_agg(const int* __restrict__ off,
                                             const int* __restrict__ esrc,
                                             const float* __restrict__ dinv,
                                             const float* __restrict__ feat,
                                             const float* __restrict__ bias,
                                             float* __restrict__ outp, int N) {
    int wave = threadIdx.x >> 6;
    int lane = threadIdx.x & 63;
    int d = blockIdx.x * 4 + wave;
    if (d >= N) return;
    int lo = off[d], hi = off[d + 1];
    float dd = dinv[d];
    float acc = 0.f;
    int e = lo;
    for (; e + 4 <= hi; e += 4) {
        int s0 = esrc[e + 0], s1 = esrc[e + 1], s2 = esrc[e + 2], s3 = esrc[e + 3];
        float v0 = feat[(long long)s0 * NHID + lane];
        float v1 = feat[(long long)s1 * NHID + lane];
        float v2 = feat[(long long)s2 * NHID + lane];
        float v3 = feat[(long long)s3 * NHID + lane];
        float n0 = dinv[s0], n1 = dinv[s1], n2 = dinv[s2], n3 = dinv[s3];
        acc += n0 * v0 + n1 * v1 + n2 * v2 + n3 * v3;
    }
    for (; e < hi; ++e) {
        int s = esrc[e];
        acc += dinv[s] * feat[(long long)s * NHID + lane];
    }
    acc *= dd;                                          // fold dst-side norm
    acc += dd * dd * feat[(long long)d * NHID + lane];  // self loop
    if (BIAS) acc += bias[lane];
    if (RELU) acc = fmaxf(acc, 0.f);
    outp[(long long)d * NHID + lane] = acc;
}

extern "C" void kernel_launch(void* const* d_in, const int* in_sizes, int n_in,
                              void* d_out, int out_size, void* d_ws, size_t ws_size,
                              hipStream_t stream) {
    const float* x  = (const float*)d_in[0];
    const int*   ei = (const int*)d_in[1];
    const float* W1 = (const float*)d_in[2];
    const float* b1 = (const float*)d_in[3];
    const float* W2 = (const float*)d_in[4];
    const float* b2 = (const float*)d_in[5];
    float* out = (float*)d_out;

    const int N = in_sizes[0] / NFEAT;          // 100000
    const long long E = in_sizes[1] / 2;        // 1600000
    const int nchunks = (N + 1 + 1023) / 1024;  // scan chunks (<=256 required)

    // workspace layout
    char* w = (char*)d_ws;
    int*   flag     = (int*)w;                          // 4 B (pad 256)
    int*   cnt      = (int*)(w + 256);                  // N
    int*   off      = cnt + N;                          // N+1
    int*   cursor   = off + N + 1;                      // N
    int*   chunksum = cursor + N;                       // 256
    int*   chunkoff = chunksum + 256;                   // 256
    float* dinv     = (float*)(chunkoff + 256);         // N
    int*   esrc     = (int*)(dinv + N);                 // E
    float* xw1      = (float*)(esrc + E);               // N*64
    float* h        = xw1 + (size_t)N * NHID;           // N*64
    float* agg2     = h + (size_t)N * NHID;             // N*64

    hipMemsetAsync(cnt, 0, (size_t)N * sizeof(int), stream);

    k_detect<<<1, 256, 0, stream>>>(ei, 4096, flag);
    k_count<<<(int)((E + 255) / 256), 256, 0, stream>>>(ei, flag, E, cnt);
    k_dinv<<<(N + 255) / 256, 256, 0, stream>>>(cnt, dinv, N);

    k_scan1<<<nchunks, 256, 0, stream>>>(cnt, N, off, chunksum);
    k_scan2<<<1, 256, 0, stream>>>(chunksum, chunkoff, nchunks);
    k_scan3<<<(N + 1 + 255) / 256, 256, 0, stream>>>(off, chunkoff, N, cursor);
    k_fill<<<(int)((E + 255) / 256), 256, 0, stream>>>(ei, flag, E, cursor, esrc);

    k_gemm1<<<(N + 63) / 64, 256, 0, stream>>>(x, W1, xw1, N);

    // layer 1 aggregate + self-loop + bias + relu -> h
    k_agg<1, 1><<<(N + 3) / 4, 256, 0, stream>>>(off, esrc, dinv, xw1, b1, h, N);
    // layer 2 aggregate (no bias/relu) -> agg2
    k_agg<0, 0><<<(N + 3) / 4, 256, 0, stream>>>(off, esrc, dinv, h, nullptr, agg2, N);

    int ntiles = (N + 63) / 64;
    int g2grid = ntiles < 768 ? ntiles : 768;
    k_gemm2<<<g2grid, 256, 0, stream>>>(agg2, W2, b2, out, N, ntiles);
}

// Round 4
// 393.905 us; speedup vs baseline: 11.2498x; 1.3623x over previous
//
#include <hip/hip_runtime.h>

#define NFEAT 128
#define NHID 64
#define MAXB 1024          // max dst buckets (node>>8), supports N<=262144
#define BSHIFT 8
#define BNODES 256

// ---------- edge-index dtype detection ----------
// JAX reference says int64 but default JAX config downcasts to int32.
// Little-endian int64 with values < 2^31 => every odd int32 word is 0.
__global__ void k_detect(const int* __restrict__ ei_words, int nwords, int* flag) {
    __shared__ int s_or;
    if (threadIdx.x == 0) s_or = 0;
    __syncthreads();
    int acc = 0;
    for (int i = 1 + 2 * (int)threadIdx.x; i < nwords; i += 2 * (int)blockDim.x)
        acc |= ei_words[i];
    atomicOr(&s_or, acc);
    __syncthreads();
    if (threadIdx.x == 0) *flag = (s_or == 0) ? 1 : 0;
}

__device__ __forceinline__ int edge_idx(const int* __restrict__ ei, int is64,
                                        long long E, long long e, int which) {
    long long pos = which ? (E + e) : e;
    return is64 ? ei[2 * pos] : ei[pos];
}

// ---------- bucket histogram (LDS-privatized) ----------
__global__ __launch_bounds__(256) void k_bhist(const int* __restrict__ ei,
                                               const int* __restrict__ flag,
                                               long long E, int* gbhist, int NB) {
    __shared__ int hist[MAXB];
    for (int i = threadIdx.x; i < NB; i += 256) hist[i] = 0;
    __syncthreads();
    int is64 = *flag;
    long long stride = (long long)gridDim.x * 256;
    for (long long e = (long long)blockIdx.x * 256 + threadIdx.x; e < E; e += stride) {
        int d = edge_idx(ei, is64, E, e, 1);
        atomicAdd(&hist[d >> BSHIFT], 1);
    }
    __syncthreads();
    for (int i = threadIdx.x; i < NB; i += 256)
        if (hist[i]) atomicAdd(&gbhist[i], hist[i]);
}

// ---------- scan bucket totals (1 block); also writes off[N]=E ----------
__global__ __launch_bounds__(256) void k_bscan(const int* __restrict__ gbhist, int NB,
                                               int* boff, int* bcur, int* offN) {
    __shared__ int s[256];
    int t = threadIdx.x;
    int v[4]; int sum = 0;
#pragma unroll
    for (int j = 0; j < 4; ++j) {
        int i = t * 4 + j;
        v[j] = (i < NB) ? gbhist[i] : 0;
        sum += v[j];
    }
    s[t] = sum;
    __syncthreads();
    for (int d = 1; d < 256; d <<= 1) {
        int val = (t >= d) ? s[t - d] : 0;
        __syncthreads();
        s[t] += val;
        __syncthreads();
    }
    int run = s[t] - sum;   // exclusive
#pragma unroll
    for (int j = 0; j < 4; ++j) {
        int i = t * 4 + j;
        if (i <= NB) boff[i] = run;
        if (i < NB)  bcur[i] = run;
        run += v[j];
    }
    if (t == 255) *offN = s[255];   // off[N] = E
}

// ---------- partition edges into dst buckets (LDS cursors, 8B records) ----------
__global__ __launch_bounds__(256) void k_partition(const int* __restrict__ ei,
                                                   const int* __restrict__ flag,
                                                   long long E, int* bcur,
                                                   uint2* __restrict__ staging,
                                                   int NB, long long perblk) {
    __shared__ int hist[MAXB];
    __shared__ int cur[MAXB];
    for (int i = threadIdx.x; i < NB; i += 256) hist[i] = 0;
    __syncthreads();
    long long lo = (long long)blockIdx.x * perblk;
    long long hi = lo + perblk; if (hi > E) hi = E;
    int is64 = *flag;
    for (long long e = lo + threadIdx.x; e < hi; e += 256) {
        int d = edge_idx(ei, is64, E, e, 1);
        atomicAdd(&hist[d >> BSHIFT], 1);
    }
    __syncthreads();
    for (int i = threadIdx.x; i < NB; i += 256)
        cur[i] = hist[i] ? atomicAdd(&bcur[i], hist[i]) : 0;
    __syncthreads();
    for (long long e = lo + threadIdx.x; e < hi; e += 256) {
        int s = edge_idx(ei, is64, E, e, 0);
        int d = edge_idx(ei, is64, E, e, 1);
        int pos = atomicAdd(&cur[d >> BSHIFT], 1);
        staging[pos] = make_uint2((unsigned)s, (unsigned)d);
    }
}

// ---------- per-bucket CSR: node counts, scan, fill esrc; emit off & dinv ----------
__global__ __launch_bounds__(256) void k_bucket(const uint2* __restrict__ staging,
                                                const int* __restrict__ boff,
                                                int N, int* off, int* esrc, float* dinv) {
    __shared__ int cnt_s[BNODES];
    __shared__ int scan_s[BNODES];
    int b = blockIdx.x;
    int base = b << BSHIFT;
    int t = threadIdx.x;
    cnt_s[t] = 0;
    __syncthreads();
    int lo = boff[b], hi = boff[b + 1];
    for (int e = lo + t; e < hi; e += 256)
        atomicAdd(&cnt_s[staging[e].y - base], 1);
    __syncthreads();
    int v = cnt_s[t];
    scan_s[t] = v;
    __syncthreads();
    for (int d = 1; d < 256; d <<= 1) {
        int val = (t >= d) ? scan_s[t - d] : 0;
        __syncthreads();
        scan_s[t] += val;
        __syncthreads();
    }
    int excl = scan_s[t] - v;
    int node = base + t;
    if (node < N) {
        off[node] = lo + excl;
        dinv[node] = rsqrtf((float)v + 1.0f);   // +1 self loop
    }
    __syncthreads();
    cnt_s[t] = lo + excl;   // reuse as cursor
    __syncthreads();
    for (int e = lo + t; e < hi; e += 256) {
        uint2 sd = staging[e];
        int pos = atomicAdd(&cnt_s[sd.y - base], 1);
        esrc[pos] = (int)sd.x;
    }
}

// ---------- register-blocked fp32 GEMM helpers ----------
__device__ __forceinline__ void fma4(float (&acc)[4], float a, const float4& b) {
    acc[0] += a * b.x; acc[1] += a * b.y; acc[2] += a * b.z; acc[3] += a * b.w;
}

// ---------- GEMM1: x[N,128] @ W1[128,64], scaled by dinv[row] -> xw1s[N,64] ----------
__global__ __launch_bounds__(256) void k_gemm1(const float* __restrict__ x,
                                               const float* __restrict__ W1,
                                               const float* __restrict__ dinv,
                                               float* __restrict__ xw1s, int N) {
    __shared__ float sA[64 * NFEAT];   // 32 KB
    __shared__ float sB[NFEAT * NHID]; // 32 KB
    for (int i = threadIdx.x; i < NFEAT * NHID / 4; i += 256)
        ((float4*)sB)[i] = ((const float4*)W1)[i];
    int row0 = blockIdx.x * 64;
    for (int i = threadIdx.x; i < 64 * NFEAT / 4; i += 256) {
        int r = i >> 5, c4 = i & 31;
        int row = row0 + r;
        ((float4*)sA)[i] = (row < N) ? ((const float4*)x)[(long long)row * 32 + c4]
                                     : make_float4(0.f, 0.f, 0.f, 0.f);
    }
    __syncthreads();
    int rg = threadIdx.x >> 4;
    int cg = threadIdx.x & 15;
    int r0 = rg * 4, c0 = cg * 4;
    float acc[4][4] = {};
#pragma unroll 4
    for (int k = 0; k < NFEAT; k += 4) {
        float4 a0 = *(const float4*)&sA[(r0 + 0) * NFEAT + k];
        float4 a1 = *(const float4*)&sA[(r0 + 1) * NFEAT + k];
        float4 a2 = *(const float4*)&sA[(r0 + 2) * NFEAT + k];
        float4 a3 = *(const float4*)&sA[(r0 + 3) * NFEAT + k];
        float4 b0 = *(const float4*)&sB[(k + 0) * NHID + c0];
        float4 b1 = *(const float4*)&sB[(k + 1) * NHID + c0];
        float4 b2v = *(const float4*)&sB[(k + 2) * NHID + c0];
        float4 b3 = *(const float4*)&sB[(k + 3) * NHID + c0];
        fma4(acc[0], a0.x, b0); fma4(acc[0], a0.y, b1); fma4(acc[0], a0.z, b2v); fma4(acc[0], a0.w, b3);
        fma4(acc[1], a1.x, b0); fma4(acc[1], a1.y, b1); fma4(acc[1], a1.z, b2v); fma4(acc[1], a1.w, b3);
        fma4(acc[2], a2.x, b0); fma4(acc[2], a2.y, b1); fma4(acc[2], a2.z, b2v); fma4(acc[2], a2.w, b3);
        fma4(acc[3], a3.x, b0); fma4(acc[3], a3.y, b1); fma4(acc[3], a3.z, b2v); fma4(acc[3], a3.w, b3);
    }
#pragma unroll
    for (int r = 0; r < 4; ++r) {
        int row = row0 + r0 + r;
        if (row < N) {
            float di = dinv[row];
            float4 o = make_float4(di * acc[r][0], di * acc[r][1],
                                   di * acc[r][2], di * acc[r][3]);
            *(float4*)&xw1s[(long long)row * NHID + c0] = o;
        }
    }
}

// ---------- aggregation over pre-scaled features ----------
// feat is pre-scaled by dinv[src]. raw = dd*(sum_edges feat[s] + feat[d]).
// MODE 1: out = dd * relu(raw + bias)   (stores layer-1 h pre-scaled)
// MODE 0: out = raw
template <int MODE>
__global__ __launch_bounds__(256) void k_agg(const int* __restrict__ off,
                                             const int* __restrict__ esrc,
                                             const float* __restrict__ dinv,
                                             const float* __restrict__ feat,
                                             const float* __restrict__ bias,
                                             float* __restrict__ outp, int N) {
    int wave = threadIdx.x >> 6;
    int lane = threadIdx.x & 63;
    int d = blockIdx.x * 4 + wave;
    if (d >= N) return;
    int lo = off[d], hi = off[d + 1];
    float dd = dinv[d];
    float acc = 0.f;
    int e = lo;
    for (; e + 8 <= hi; e += 8) {
        int s0 = esrc[e + 0], s1 = esrc[e + 1], s2 = esrc[e + 2], s3 = esrc[e + 3];
        int s4 = esrc[e + 4], s5 = esrc[e + 5], s6 = esrc[e + 6], s7 = esrc[e + 7];
        float v0 = feat[(long long)s0 * NHID + lane];
        float v1 = feat[(long long)s1 * NHID + lane];
        float v2 = feat[(long long)s2 * NHID + lane];
        float v3 = feat[(long long)s3 * NHID + lane];
        float v4 = feat[(long long)s4 * NHID + lane];
        float v5 = feat[(long long)s5 * NHID + lane];
        float v6 = feat[(long long)s6 * NHID + lane];
        float v7 = feat[(long long)s7 * NHID + lane];
        acc += ((v0 + v1) + (v2 + v3)) + ((v4 + v5) + (v6 + v7));
    }
    for (; e < hi; ++e)
        acc += feat[(long long)esrc[e] * NHID + lane];
    acc += feat[(long long)d * NHID + lane];   // self loop (pre-scaled)
    float raw = dd * acc;
    if (MODE == 1) {
        float v = fmaxf(raw + bias[lane], 0.f);
        outp[(long long)d * NHID + lane] = dd * v;   // pre-scale for layer 2
    } else {
        outp[(long long)d * NHID + lane] = raw;
    }
}

// ---------- GEMM2: agg2[N,64] @ W2[64,128] + b2 -> out[N,128] ----------
__global__ __launch_bounds__(256) void k_gemm2(const float* __restrict__ h,
                                               const float* __restrict__ W2,
                                               const float* __restrict__ b2,
                                               float* __restrict__ out, int N, int ntiles) {
    __shared__ float sB[NHID * NFEAT]; // 32 KB
    __shared__ float sA[64 * NHID];    // 16 KB
    for (int i = threadIdx.x; i < NHID * NFEAT / 4; i += 256)
        ((float4*)sB)[i] = ((const float4*)W2)[i];
    int rg = threadIdx.x >> 5;
    int cg = threadIdx.x & 31;
    int c0 = cg * 4;
    float4 bias = *(const float4*)&b2[c0];
    for (int tile = blockIdx.x; tile < ntiles; tile += gridDim.x) {
        int row0 = tile * 64;
        __syncthreads();
        for (int i = threadIdx.x; i < 64 * NHID / 4; i += 256) {
            int r = i >> 4, c4 = i & 15;
            int row = row0 + r;
            ((float4*)sA)[i] = (row < N) ? ((const float4*)h)[(long long)row * 16 + c4]
                                         : make_float4(0.f, 0.f, 0.f, 0.f);
        }
        __syncthreads();
        float acc[8][4] = {};
#pragma unroll 2
        for (int k = 0; k < NHID; k += 4) {
            float4 b0 = *(const float4*)&sB[(k + 0) * NFEAT + c0];
            float4 b1 = *(const float4*)&sB[(k + 1) * NFEAT + c0];
            float4 b2f = *(const float4*)&sB[(k + 2) * NFEAT + c0];
            float4 b3 = *(const float4*)&sB[(k + 3) * NFEAT + c0];
#pragma unroll
            for (int r = 0; r < 8; ++r) {
                float4 a = *(const float4*)&sA[(rg * 8 + r) * NHID + k];
                fma4(acc[r], a.x, b0); fma4(acc[r], a.y, b1);
                fma4(acc[r], a.z, b2f); fma4(acc[r], a.w, b3);
            }
        }
#pragma unroll
        for (int r = 0; r < 8; ++r) {
            int row = row0 + rg * 8 + r;
            if (row < N) {
                float4 o = make_float4(acc[r][0] + bias.x, acc[r][1] + bias.y,
                                       acc[r][2] + bias.z, acc[r][3] + bias.w);
                *(float4*)&out[(long long)row * NFEAT + c0] = o;
            }
        }
    }
}

extern "C" void kernel_launch(void* const* d_in, const int* in_sizes, int n_in,
                              void* d_out, int out_size, void* d_ws, size_t ws_size,
                              hipStream_t stream) {
    const float* x  = (const float*)d_in[0];
    const int*   ei = (const int*)d_in[1];
    const float* W1 = (const float*)d_in[2];
    const float* b1 = (const float*)d_in[3];
    const float* W2 = (const float*)d_in[4];
    const float* b2 = (const float*)d_in[5];
    float* out = (float*)d_out;

    const int N = in_sizes[0] / NFEAT;            // 100000
    const long long E = in_sizes[1] / 2;          // 1600000
    const int NB = (N + BNODES - 1) >> BSHIFT;    // 391 buckets

    // workspace layout
    char* w = (char*)d_ws;
    int*   flag   = (int*)w;                         // pad 256 B
    int*   gbhist = (int*)(w + 256);                 // MAXB
    int*   boff   = gbhist + MAXB;                   // MAXB+1
    int*   bcur   = boff + MAXB + 1;                 // MAXB
    float* dinv   = (float*)(bcur + MAXB);           // N
    int*   off    = (int*)(dinv + N);                // N+1
    char*  p      = (char*)(off + N + 1);
    p = (char*)(((uintptr_t)p + 255) & ~(uintptr_t)255);
    uint2* staging = (uint2*)p;                      // E * 8 B
    int*   esrc   = (int*)(staging + E);             // E
    float* xw1s   = (float*)(esrc + E);              // N*64 (reused as agg2)
    float* h      = xw1s + (size_t)N * NHID;         // N*64
    float* agg2   = xw1s;                            // overlay: xw1s dead after agg1

    hipMemsetAsync(gbhist, 0, (size_t)NB * sizeof(int), stream);

    k_detect<<<1, 256, 0, stream>>>(ei, 4096, flag);
    k_bhist<<<256, 256, 0, stream>>>(ei, flag, E, gbhist, NB);
    k_bscan<<<1, 256, 0, stream>>>(gbhist, NB, boff, bcur, off + N);
    long long perblk = (E + 511) / 512;
    k_partition<<<512, 256, 0, stream>>>(ei, flag, E, bcur, staging, NB, perblk);
    k_bucket<<<NB, 256, 0, stream>>>(staging, boff, N, off, esrc, dinv);

    k_gemm1<<<(N + 63) / 64, 256, 0, stream>>>(x, W1, dinv, xw1s, N);

    // layer 1: aggregate + bias + relu, store pre-scaled -> h
    k_agg<1><<<(N + 3) / 4, 256, 0, stream>>>(off, esrc, dinv, xw1s, b1, h, N);
    // layer 2: aggregate -> agg2
    k_agg<0><<<(N + 3) / 4, 256, 0, stream>>>(off, esrc, dinv, h, nullptr, agg2, N);

    int ntiles = (N + 63) / 64;
    int g2grid = ntiles < 768 ? ntiles : 768;
    k_gemm2<<<g2grid, 256, 0, stream>>>(agg2, W2, b2, out, N, ntiles);
}